// Round 4
// baseline (252.417 us; speedup 1.0000x reference)
//
#include <hip/hip_runtime.h>
#include <hip/hip_bf16.h>

// Problem constants: x [4,32,32,16,256] -> N=65536 rows, D=256
// embeddings [256, 4096] -> D=256, K=4096
#define NROWS 65536
#define DIM   256
#define KCB   4096
#define CHUNK 32                 // codebook cols staged per chunk (16KB)
#define NCH   (KCB / CHUNK)      // 128 chunks

typedef __attribute__((ext_vector_type(8))) short bf16x8;  // 8 bf16 in 4 VGPRs
typedef __attribute__((ext_vector_type(4))) float f32x4;

__device__ inline short f2bf(float f) {
    __hip_bfloat16 h = __float2bfloat16(f);
    return *reinterpret_cast<short*>(&h);
}

// ---------------------------------------------------------------------------
// Prep 1: tiled transpose E[256][4096] -> ET32[4096][256] (f32) + ETbf (bf16)
// ---------------------------------------------------------------------------
__global__ void prep_transpose(const float* __restrict__ E,
                               float* __restrict__ ET32,
                               ushort* __restrict__ ETbf)
{
    __shared__ float tile[64][65];
    const int kb = blockIdx.x * 64;
    const int db = blockIdx.y * 64;
    const int lo = threadIdx.x & 63;
    const int hi = threadIdx.x >> 6;

#pragma unroll
    for (int i = 0; i < 16; ++i) {
        int d = i * 4 + hi;
        tile[lo][d] = E[(size_t)(db + d) * KCB + kb + lo];
    }
    __syncthreads();
#pragma unroll
    for (int i = 0; i < 16; ++i) {
        int k = i * 4 + hi;
        float v = tile[k][lo];
        size_t off = (size_t)(kb + k) * DIM + db + lo;
        ET32[off] = v;
        ETbf[off] = (ushort)f2bf(v);
    }
}

// ---------------------------------------------------------------------------
// Prep 2: negative half column norms: nenh[k] = -0.5*||e_k||^2 (fp32-exact).
// score = sim - 0.5||e||^2 (same order as 2*sim - ||e||^2); MFMA acc starts
// at nenh so the epilogue gets the score for free.
// ---------------------------------------------------------------------------
__global__ void prep_enorm(const float* __restrict__ E, float* __restrict__ nenh)
{
    int k = blockIdx.x * 256 + threadIdx.x;
    float s = 0.0f;
#pragma unroll 8
    for (int d = 0; d < DIM; ++d) {
        float v = E[(size_t)d * KCB + k];
        s = fmaf(v, v, s);
    }
    nenh[k] = -0.5f * s;
}

// ---------------------------------------------------------------------------
// vq_argmin helpers
// ---------------------------------------------------------------------------
// Stage chunk ct (CHUNK cols x 512B = 16KB) into smem[BUF]. 4 waves x 4
// issues x 1KB. LDS dest is wave-uniform base (+ HW lane*16); the XOR
// swizzle (slot ^= col&7) lives in the per-lane GLOBAL source (both-sides).
template <int BUF>
__device__ __forceinline__ void stage_chunk(
    ushort (&smem)[2][CHUNK * DIM],
    const char* const (&sbase)[4], int wave, int ct)
{
#pragma unroll
    for (int j = 0; j < 4; ++j) {
        const char* src = sbase[j] + (size_t)ct * (CHUNK * 512);
        __builtin_amdgcn_global_load_lds(
            (const __attribute__((address_space(1))) unsigned*)src,
            (__attribute__((address_space(3))) unsigned*)
                ((char*)&smem[BUF][0] + wave * 4096 + j * 1024),
            16, 0, 0);
    }
}

// Process chunk ct from smem[BUF]: 2 col-tiles x 16 MFMA + 3-op argmax update.
// All ds_read addresses = precomputed VGPR boffB[kc] + compile-time imm.
template <int BUF>
__device__ __forceinline__ void process_chunk(
    const ushort (&smem)[2][CHUNK * DIM],
    const float* __restrict__ nenh,
    const bf16x8 (&afrag)[2][8],
    const int (&boffB)[8],
    float (&best)[2][4], int (&bidx)[2][4],
    int l15, int ct)
{
#pragma unroll
    for (int tc = 0; tc < 2; ++tc) {
        const int col = ct * CHUNK + tc * 16 + l15;
        const float nh = nenh[col];
        f32x4 acc0 = {nh, nh, nh, nh};
        f32x4 acc1 = {nh, nh, nh, nh};
#pragma unroll
        for (int kh = 0; kh < 2; ++kh) {
            bf16x8 bfr[4];
#pragma unroll
            for (int k2 = 0; k2 < 4; ++k2)
                bfr[k2] = *(const bf16x8*)((const char*)&smem[BUF][0]
                                           + boffB[kh * 4 + k2] + tc * 8192);
#pragma unroll
            for (int k2 = 0; k2 < 4; ++k2) {
                acc0 = __builtin_amdgcn_mfma_f32_16x16x32_bf16(
                    afrag[0][kh * 4 + k2], bfr[k2], acc0, 0, 0, 0);
                acc1 = __builtin_amdgcn_mfma_f32_16x16x32_bf16(
                    afrag[1][kh * 4 + k2], bfr[k2], acc1, 0, 0, 0);
            }
        }
        // C/D: col = lane&15, row = (lane>>4)*4 + r  [HW-verified]
#pragma unroll
        for (int r = 0; r < 4; ++r) {
            float s0 = acc0[r];
            bool g0 = s0 > best[0][r];
            bidx[0][r] = g0 ? col : bidx[0][r];
            best[0][r] = fmaxf(best[0][r], s0);
            float s1 = acc1[r];
            bool g1 = s1 > best[1][r];
            bidx[1][r] = g1 ? col : bidx[1][r];
            best[1][r] = fmaxf(best[1][r], s1);
        }
    }
}

// ---------------------------------------------------------------------------
// Fused GEMM + argmin. Block = 4 waves x 32 rows. 128 chunks of 32 cols,
// double-buffered 2x16KB LDS -> 4 blocks/CU. k-mapping: k = g*64 + kc*8 + j
// (same sigma for A and B => contraction correct for any bijection).
// ---------------------------------------------------------------------------
__global__ __launch_bounds__(256, 4)
void vq_argmin(const float* __restrict__ X,       // [65536][256] f32
               const ushort* __restrict__ ETbf,   // [4096][256] bf16
               const float* __restrict__ nenh,    // [4096] = -0.5*||e||^2
               int* __restrict__ idxout)          // [65536]
{
    __shared__ ushort smem[2][CHUNK * DIM];       // 2 x 16KB double buffer
    const int tid  = threadIdx.x;
    const int lane = tid & 63;
    const int wave = tid >> 6;          // 0..3
    const int l15  = lane & 15;
    const int g    = lane >> 4;         // 0..3
    const int m    = l15 & 7;           // read-side swizzle key
    const long rowbase = (long)blockIdx.x * 128 + wave * 32;

    // A fragments resident in VGPRs: lane holds A[row=l15][k=g*64+kc*8+j].
    bf16x8 afrag[2][8];
#pragma unroll
    for (int rt = 0; rt < 2; ++rt) {
        const float* xr = X + (rowbase + rt * 16 + l15) * DIM;
#pragma unroll
        for (int kc = 0; kc < 8; ++kc) {
            int k0 = g * 64 + kc * 8;
            float4 v0 = *(const float4*)(xr + k0);
            float4 v1 = *(const float4*)(xr + k0 + 4);
            bf16x8 f;
            f[0] = f2bf(v0.x); f[1] = f2bf(v0.y);
            f[2] = f2bf(v0.z); f[3] = f2bf(v0.w);
            f[4] = f2bf(v1.x); f[5] = f2bf(v1.y);
            f[6] = f2bf(v1.z); f[7] = f2bf(v1.w);
            afrag[rt][kc] = f;
        }
    }

    // Precomputed per-wave LDS byte offsets: row l15 (of the 16-col tile),
    // slot (g*8 + kc) swizzled by m. ds_read_b128 = vgpr + imm, zero VALU.
    int boffB[8];
#pragma unroll
    for (int kc = 0; kc < 8; ++kc)
        boffB[kc] = l15 * 512 + g * 128 + ((kc ^ m) << 4);

    // Per-lane global source addresses for staging (XOR-swizzled; ct adds
    // a uniform CHUNK*512 stride).
    const char* sbase[4];
#pragma unroll
    for (int j = 0; j < 4; ++j) {
        const int o    = wave * 4096 + j * 1024 + lane * 16;
        const int col0 = o >> 9;           // 0..31 within chunk
        const int cph  = (o >> 4) & 31;    // physical 16B slot in row
        sbase[j] = (const char*)ETbf + ((size_t)col0 << 9)
                 + ((size_t)(cph ^ (col0 & 7)) << 4);
    }

    float best[2][4];
    int   bidx[2][4];
#pragma unroll
    for (int rt = 0; rt < 2; ++rt)
#pragma unroll
        for (int r = 0; r < 4; ++r) { best[rt][r] = -3.4e38f; bidx[rt][r] = 0x7fffffff; }

    stage_chunk<0>(smem, sbase, wave, 0);
    for (int ct = 0; ct < NCH; ct += 2) {
        __syncthreads();                              // buf0 staged
        if (ct + 1 < NCH) stage_chunk<1>(smem, sbase, wave, ct + 1);
        process_chunk<0>(smem, nenh, afrag, boffB, best, bidx, l15, ct);
        __syncthreads();                              // buf1 staged
        if (ct + 2 < NCH) stage_chunk<0>(smem, sbase, wave, ct + 2);
        process_chunk<1>(smem, nenh, afrag, boffB, best, bidx, l15, ct + 1);
    }

    // Reduce across the 16 lanes holding the same row (xor in low 4 bits).
#pragma unroll
    for (int rt = 0; rt < 2; ++rt) {
#pragma unroll
        for (int r = 0; r < 4; ++r) {
            float v = best[rt][r];
            int   ix = bidx[rt][r];
#pragma unroll
            for (int off = 1; off < 16; off <<= 1) {
                float ov = __shfl_xor(v, off, 64);
                int   oi = __shfl_xor(ix, off, 64);
                if (ov > v || (ov == v && oi < ix)) { v = ov; ix = oi; }
            }
            if (l15 == 0) {
                long row = rowbase + rt * 16 + g * 4 + r;
                idxout[row] = ix;
            }
        }
    }
}

// ---------------------------------------------------------------------------
// Gather nearest codebook rows (coalesced from ET32) + histogram
// ---------------------------------------------------------------------------
__global__ void vq_gather(const int* __restrict__ idxin,
                          const float* __restrict__ ET32,
                          float* __restrict__ out,
                          unsigned* __restrict__ counts)
{
    const int tid = threadIdx.x;
    const long n  = (long)blockIdx.x * 4 + (tid >> 6);
    const int d4  = tid & 63;
    const int idx = idxin[n];
    float4 v = *(const float4*)(ET32 + (size_t)idx * DIM + d4 * 4);
    *(float4*)(out + n * DIM + d4 * 4) = v;
    if (d4 == 0) atomicAdd(&counts[idx], 1u);
}

// ---------------------------------------------------------------------------
// Perplexity = exp(-sum p*log(p+1e-10)), p = counts/N
// ---------------------------------------------------------------------------
__global__ void vq_perplexity(const unsigned* __restrict__ counts, float* __restrict__ outp)
{
    __shared__ float wsum[4];
    const int tid = threadIdx.x;
    float s = 0.0f;
    for (int k = tid; k < KCB; k += 256) {
        float p = (float)counts[k] * (1.0f / (float)NROWS);
        s += p * logf(p + 1e-10f);
    }
#pragma unroll
    for (int off = 32; off >= 1; off >>= 1) s += __shfl_down(s, off, 64);
    if ((tid & 63) == 0) wsum[tid >> 6] = s;
    __syncthreads();
    if (tid == 0) outp[0] = expf(-(wsum[0] + wsum[1] + wsum[2] + wsum[3]));
}

// ---------------------------------------------------------------------------
extern "C" void kernel_launch(void* const* d_in, const int* in_sizes, int n_in,
                              void* d_out, int out_size, void* d_ws, size_t ws_size,
                              hipStream_t stream)
{
    const float* X = (const float*)d_in[0];
    const float* E = (const float*)d_in[1];
    float* out = (float*)d_out;

    char* ws = (char*)d_ws;
    float*    ET32   = (float*)ws;                                   // 4 MB
    ushort*   ETbf   = (ushort*)(ws + (size_t)KCB * DIM * 4);        // 2 MB
    float*    nenh   = (float*)(ws + (size_t)KCB * DIM * 6);         // 16 KB
    int*      idxbuf = (int*)(ws + (size_t)KCB * DIM * 6 + KCB * 4); // 256 KB
    unsigned* counts = (unsigned*)(ws + (size_t)KCB * DIM * 6 + KCB * 4 + NROWS * 4); // 16 KB

    hipMemsetAsync(counts, 0, KCB * sizeof(unsigned), stream);

    dim3 b256(256);
    prep_transpose<<<dim3(KCB / 64, DIM / 64), b256, 0, stream>>>(E, ET32, ETbf);
    prep_enorm<<<KCB / 256, b256, 0, stream>>>(E, nenh);
    vq_argmin<<<NROWS / 128, b256, 0, stream>>>(X, ETbf, nenh, idxbuf);
    vq_gather<<<NROWS / 4, b256, 0, stream>>>(idxbuf, ET32, out, counts);
    vq_perplexity<<<1, b256, 0, stream>>>(counts, out + (size_t)NROWS * DIM);
}

// Round 5
// 235.640 us; speedup vs baseline: 1.0712x; 1.0712x over previous
//
#include <hip/hip_runtime.h>
#include <hip/hip_bf16.h>

// Problem constants: x [4,32,32,16,256] -> N=65536 rows, D=256
// embeddings [256, 4096] -> D=256, K=4096
#define NROWS 65536
#define DIM   256
#define KCB   4096
#define CHUNK 64                 // codebook cols staged per chunk (32KB)
#define NCH   (KCB / CHUNK)      // 64 chunks

typedef __attribute__((ext_vector_type(8))) short bf16x8;  // 8 bf16 in 4 VGPRs
typedef __attribute__((ext_vector_type(4))) float f32x4;

__device__ inline short f2bf(float f) {
    __hip_bfloat16 h = __float2bfloat16(f);
    return *reinterpret_cast<short*>(&h);
}

// ---------------------------------------------------------------------------
// Prep 1: tiled transpose E[256][4096] -> ET32[4096][256] (f32) + ETbf (bf16)
// ---------------------------------------------------------------------------
__global__ void prep_transpose(const float* __restrict__ E,
                               float* __restrict__ ET32,
                               ushort* __restrict__ ETbf)
{
    __shared__ float tile[64][65];
    const int kb = blockIdx.x * 64;
    const int db = blockIdx.y * 64;
    const int lo = threadIdx.x & 63;
    const int hi = threadIdx.x >> 6;

#pragma unroll
    for (int i = 0; i < 16; ++i) {
        int d = i * 4 + hi;
        tile[lo][d] = E[(size_t)(db + d) * KCB + kb + lo];
    }
    __syncthreads();
#pragma unroll
    for (int i = 0; i < 16; ++i) {
        int k = i * 4 + hi;
        float v = tile[k][lo];
        size_t off = (size_t)(kb + k) * DIM + db + lo;
        ET32[off] = v;
        ETbf[off] = (ushort)f2bf(v);
    }
}

// ---------------------------------------------------------------------------
// Prep 2: nenh[k] = -0.5*||e_k||^2 (fp32-exact); score = sim + nenh.
// ---------------------------------------------------------------------------
__global__ void prep_enorm(const float* __restrict__ E, float* __restrict__ nenh)
{
    int k = blockIdx.x * 256 + threadIdx.x;
    float s = 0.0f;
#pragma unroll 8
    for (int d = 0; d < DIM; ++d) {
        float v = E[(size_t)d * KCB + k];
        s = fmaf(v, v, s);
    }
    nenh[k] = -0.5f * s;
}

// ---------------------------------------------------------------------------
// vq_argmin helpers.  Block = 2 waves x 64 rows = 128 rows.
// ---------------------------------------------------------------------------
// Stage chunk ct (64 cols x 512B = 32KB). 2 waves x 16 issues x 1KB.
// LDS dest linear (wave-uniform base + HW lane*16); XOR swizzle
// (slot ^= col&7) pre-applied to the per-lane GLOBAL source offset.
template <int BUF>
__device__ __forceinline__ void stage_chunk(
    ushort (&smem)[2][CHUNK * DIM],
    const char* __restrict__ etb, const int (&soff)[16], int wave, int ct)
{
    const char* base = etb + (size_t)ct * (CHUNK * 512);
#pragma unroll
    for (int j = 0; j < 16; ++j) {
        __builtin_amdgcn_global_load_lds(
            (const __attribute__((address_space(1))) unsigned*)(base + soff[j]),
            (__attribute__((address_space(3))) unsigned*)
                ((char*)&smem[BUF][0] + wave * 16384 + j * 1024),
            16, 0, 0);
    }
}

// Process chunk ct from smem[BUF]: 4 col-tiles x (8 ds_read + 32 MFMA) +
// 3-op argmax per output. ds_read addr = VGPR boffB[kc] + compile-time imm.
template <int BUF>
__device__ __forceinline__ void process_chunk(
    const ushort (&smem)[2][CHUNK * DIM],
    const float* __restrict__ nenh,
    const bf16x8 (&afrag)[4][8],
    const int (&boffB)[8],
    float (&best)[4][4], int (&bidx)[4][4],
    int l15, int ct)
{
#pragma unroll
    for (int tc = 0; tc < 4; ++tc) {
        const int col = ct * CHUNK + tc * 16 + l15;
        const float nh = nenh[col];
        f32x4 acc[4];
#pragma unroll
        for (int rt = 0; rt < 4; ++rt) acc[rt] = {nh, nh, nh, nh};
        bf16x8 bfr[8];
#pragma unroll
        for (int kc = 0; kc < 8; ++kc)
            bfr[kc] = *(const bf16x8*)((const char*)&smem[BUF][0]
                                       + boffB[kc] + tc * 8192);
#pragma unroll
        for (int kc = 0; kc < 8; ++kc)
#pragma unroll
            for (int rt = 0; rt < 4; ++rt)
                acc[rt] = __builtin_amdgcn_mfma_f32_16x16x32_bf16(
                    afrag[rt][kc], bfr[kc], acc[rt], 0, 0, 0);
        // C/D: col = lane&15, row = (lane>>4)*4 + r  [HW-verified]
#pragma unroll
        for (int rt = 0; rt < 4; ++rt)
#pragma unroll
            for (int r = 0; r < 4; ++r) {
                float s = acc[rt][r];
                bool gt = s > best[rt][r];
                bidx[rt][r] = gt ? col : bidx[rt][r];
                best[rt][r] = fmaxf(best[rt][r], s);
            }
    }
}

// ---------------------------------------------------------------------------
// Fused GEMM + argmin. 2 waves x 64 rows/wave; 64 chunks of 64 cols,
// double-buffered 2x32KB LDS (64KB -> 2 blocks/CU, grid 512 = 2/CU).
// k-mapping: k = g*64 + kc*8 + j, same sigma for A and B (bijection-safe).
// ---------------------------------------------------------------------------
__global__ __launch_bounds__(128, 1)
void vq_argmin(const float* __restrict__ X,       // [65536][256] f32
               const ushort* __restrict__ ETbf,   // [4096][256] bf16
               const float* __restrict__ nenh,    // [4096] = -0.5*||e||^2
               int* __restrict__ idxout)          // [65536]
{
    __shared__ ushort smem[2][CHUNK * DIM];       // 2 x 32KB double buffer
    const int tid  = threadIdx.x;
    const int lane = tid & 63;
    const int wave = tid >> 6;          // 0..1
    const int l15  = lane & 15;
    const int g    = lane >> 4;         // 0..3
    const int m    = l15 & 7;           // read-side swizzle key
    const long rowbase = (long)blockIdx.x * 128 + wave * 64;

    // Per-lane global source offsets for staging (XOR-swizzled).
    // Issue j covers cols {wave*32+2j, +1}: col0 = wave*32 + 2j + (lane>>5),
    // slot = lane&31, swizzled slot = slot ^ (col0&7).
    int soff[16];
#pragma unroll
    for (int j = 0; j < 16; ++j) {
        const int o    = wave * 16384 + j * 1024 + lane * 16;
        const int col0 = o >> 9;
        const int cph  = (o >> 4) & 31;
        soff[j] = (col0 << 9) + ((cph ^ (col0 & 7)) << 4);
    }

    stage_chunk<0>(smem, (const char*)ETbf, soff, wave, 0);

    // A fragments resident in VGPRs: lane holds A[row=l15][k=g*64+kc*8+j],
    // rows rowbase + rt*16 + l15, rt = 0..3 (64 rows/wave).
    bf16x8 afrag[4][8];
#pragma unroll
    for (int rt = 0; rt < 4; ++rt) {
        const float* xr = X + (rowbase + rt * 16 + l15) * DIM;
#pragma unroll
        for (int kc = 0; kc < 8; ++kc) {
            int k0 = g * 64 + kc * 8;
            float4 v0 = *(const float4*)(xr + k0);
            float4 v1 = *(const float4*)(xr + k0 + 4);
            bf16x8 f;
            f[0] = f2bf(v0.x); f[1] = f2bf(v0.y);
            f[2] = f2bf(v0.z); f[3] = f2bf(v0.w);
            f[4] = f2bf(v1.x); f[5] = f2bf(v1.y);
            f[6] = f2bf(v1.z); f[7] = f2bf(v1.w);
            afrag[rt][kc] = f;
        }
    }

    // LDS read offsets: row l15 of the 16-col tile, slot (g*8+kc) ^ m.
    int boffB[8];
#pragma unroll
    for (int kc = 0; kc < 8; ++kc)
        boffB[kc] = l15 * 512 + ((((g << 3) + kc) ^ m) << 4);

    float best[4][4];
    int   bidx[4][4];
#pragma unroll
    for (int rt = 0; rt < 4; ++rt)
#pragma unroll
        for (int r = 0; r < 4; ++r) { best[rt][r] = -3.4e38f; bidx[rt][r] = 0x7fffffff; }

    for (int ct = 0; ct < NCH; ct += 2) {
        __syncthreads();                              // buf0 staged
        if (ct + 1 < NCH) stage_chunk<1>(smem, (const char*)ETbf, soff, wave, ct + 1);
        process_chunk<0>(smem, nenh, afrag, boffB, best, bidx, l15, ct);
        __syncthreads();                              // buf1 staged
        if (ct + 2 < NCH) stage_chunk<0>(smem, (const char*)ETbf, soff, wave, ct + 2);
        process_chunk<1>(smem, nenh, afrag, boffB, best, bidx, l15, ct + 1);
    }

    // Reduce across the 16 lanes holding the same row (xor in low 4 bits).
#pragma unroll
    for (int rt = 0; rt < 4; ++rt) {
#pragma unroll
        for (int r = 0; r < 4; ++r) {
            float v = best[rt][r];
            int   ix = bidx[rt][r];
#pragma unroll
            for (int off = 1; off < 16; off <<= 1) {
                float ov = __shfl_xor(v, off, 64);
                int   oi = __shfl_xor(ix, off, 64);
                if (ov > v || (ov == v && oi < ix)) { v = ov; ix = oi; }
            }
            if (l15 == 0) {
                long row = rowbase + rt * 16 + g * 4 + r;
                idxout[row] = ix;
            }
        }
    }
}

// ---------------------------------------------------------------------------
// Gather nearest codebook rows (coalesced from ET32) + histogram
// ---------------------------------------------------------------------------
__global__ void vq_gather(const int* __restrict__ idxin,
                          const float* __restrict__ ET32,
                          float* __restrict__ out,
                          unsigned* __restrict__ counts)
{
    const int tid = threadIdx.x;
    const long n  = (long)blockIdx.x * 4 + (tid >> 6);
    const int d4  = tid & 63;
    const int idx = idxin[n];
    float4 v = *(const float4*)(ET32 + (size_t)idx * DIM + d4 * 4);
    *(float4*)(out + n * DIM + d4 * 4) = v;
    if (d4 == 0) atomicAdd(&counts[idx], 1u);
}

// ---------------------------------------------------------------------------
// Perplexity = exp(-sum p*log(p+1e-10)), p = counts/N
// ---------------------------------------------------------------------------
__global__ void vq_perplexity(const unsigned* __restrict__ counts, float* __restrict__ outp)
{
    __shared__ float wsum[4];
    const int tid = threadIdx.x;
    float s = 0.0f;
    for (int k = tid; k < KCB; k += 256) {
        float p = (float)counts[k] * (1.0f / (float)NROWS);
        s += p * logf(p + 1e-10f);
    }
#pragma unroll
    for (int off = 32; off >= 1; off >>= 1) s += __shfl_down(s, off, 64);
    if ((tid & 63) == 0) wsum[tid >> 6] = s;
    __syncthreads();
    if (tid == 0) outp[0] = expf(-(wsum[0] + wsum[1] + wsum[2] + wsum[3]));
}

// ---------------------------------------------------------------------------
extern "C" void kernel_launch(void* const* d_in, const int* in_sizes, int n_in,
                              void* d_out, int out_size, void* d_ws, size_t ws_size,
                              hipStream_t stream)
{
    const float* X = (const float*)d_in[0];
    const float* E = (const float*)d_in[1];
    float* out = (float*)d_out;

    char* ws = (char*)d_ws;
    float*    ET32   = (float*)ws;                                   // 4 MB
    ushort*   ETbf   = (ushort*)(ws + (size_t)KCB * DIM * 4);        // 2 MB
    float*    nenh   = (float*)(ws + (size_t)KCB * DIM * 6);         // 16 KB
    int*      idxbuf = (int*)(ws + (size_t)KCB * DIM * 6 + KCB * 4); // 256 KB
    unsigned* counts = (unsigned*)(ws + (size_t)KCB * DIM * 6 + KCB * 4 + NROWS * 4); // 16 KB

    hipMemsetAsync(counts, 0, KCB * sizeof(unsigned), stream);

    prep_transpose<<<dim3(KCB / 64, DIM / 64), dim3(256), 0, stream>>>(E, ET32, ETbf);
    prep_enorm<<<KCB / 256, dim3(256), 0, stream>>>(E, nenh);
    vq_argmin<<<NROWS / 128, dim3(128), 0, stream>>>(X, ETbf, nenh, idxbuf);
    vq_gather<<<NROWS / 4, dim3(256), 0, stream>>>(idxbuf, ET32, out, counts);
    vq_perplexity<<<1, dim3(256), 0, stream>>>(counts, out + (size_t)NROWS * DIM);
}

// Round 6
// 191.928 us; speedup vs baseline: 1.3152x; 1.2277x over previous
//
#include <hip/hip_runtime.h>
#include <hip/hip_bf16.h>

// Problem constants: x [4,32,32,16,256] -> N=65536 rows, D=256
// embeddings [256, 4096] -> D=256, K=4096
#define NROWS 65536
#define DIM   256
#define KCB   4096
#define CHUNK 32                 // codebook cols per chunk (16KB)
#define NCH   (KCB / CHUNK)      // 128 chunks
#define NBUF  4                  // buffer ring depth
#define BUFB  16384              // bytes per buffer
#define NENHB 16384              // nenh LDS bytes (4096 f32)

typedef __attribute__((ext_vector_type(8))) short bf16x8;  // 8 bf16, 4 VGPRs
typedef __attribute__((ext_vector_type(4))) float f32x4;

#define WAITV(n) asm volatile("s_waitcnt vmcnt(" #n ")" ::: "memory")

__device__ inline short f2bf(float f) {
    __hip_bfloat16 h = __float2bfloat16(f);
    return *reinterpret_cast<short*>(&h);
}

// ---------------------------------------------------------------------------
// Prep 1: tiled transpose E[256][4096] -> ET32[4096][256] (f32) + ETbf (bf16)
// ---------------------------------------------------------------------------
__global__ void prep_transpose(const float* __restrict__ E,
                               float* __restrict__ ET32,
                               ushort* __restrict__ ETbf)
{
    __shared__ float tile[64][65];
    const int kb = blockIdx.x * 64;
    const int db = blockIdx.y * 64;
    const int lo = threadIdx.x & 63;
    const int hi = threadIdx.x >> 6;

#pragma unroll
    for (int i = 0; i < 16; ++i) {
        int d = i * 4 + hi;
        tile[lo][d] = E[(size_t)(db + d) * KCB + kb + lo];
    }
    __syncthreads();
#pragma unroll
    for (int i = 0; i < 16; ++i) {
        int k = i * 4 + hi;
        float v = tile[k][lo];
        size_t off = (size_t)(kb + k) * DIM + db + lo;
        ET32[off] = v;
        ETbf[off] = (ushort)f2bf(v);
    }
}

// ---------------------------------------------------------------------------
// Prep 2: nenh[k] = -0.5*||e_k||^2 (fp32-exact); score = sim + nenh.
// ---------------------------------------------------------------------------
__global__ void prep_enorm(const float* __restrict__ E, float* __restrict__ nenh)
{
    int k = blockIdx.x * 256 + threadIdx.x;
    float s = 0.0f;
#pragma unroll 8
    for (int d = 0; d < DIM; ++d) {
        float v = E[(size_t)d * KCB + k];
        s = fmaf(v, v, s);
    }
    nenh[k] = -0.5f * s;
}

// ---------------------------------------------------------------------------
// vq_argmin: 4 waves x 32 rows = 128 rows/block; 128 chunks of 32 cols.
// 4-deep LDS buffer ring + counted vmcnt (T3/T4): stage chunk ct+3 while
// computing ct; loop wait = vmcnt(8) (forces ct's stages retired, leaves
// ct+1/ct+2 in flight); ONE barrier per chunk; nenh lives in LDS so the
// K-loop issues no global loads (any would FIFO-drain the stage queue).
// LDS map: [0,16K) nenh f32; [16K+B*16K, +16K) buffer B. 80KB -> 2 blk/CU.
// ---------------------------------------------------------------------------
__shared__ char lds_raw[NENHB + NBUF * BUFB];

// Stage chunk ct (32 cols x 512B = 16KB) into buffer BUF. 4 waves x 4 issues
// x 1KB. LDS dest linear; XOR swizzle (slot ^= col&7) pre-applied to the
// per-lane GLOBAL source offset (both-sides rule, verified R4/R5).
template <int BUF>
__device__ __forceinline__ void stage_chunk(
    const char* __restrict__ etb, const int (&soff)[4], int wave, int ct)
{
    const char* base = etb + (size_t)ct * (CHUNK * 512);
#pragma unroll
    for (int j = 0; j < 4; ++j) {
        __builtin_amdgcn_global_load_lds(
            (const __attribute__((address_space(1))) unsigned*)(base + soff[j]),
            (__attribute__((address_space(3))) unsigned*)
                (lds_raw + NENHB + BUF * BUFB + wave * 4096 + j * 1024),
            16, 0, 0);
    }
}

// Process chunk ct from buffer BUF: 2 col-tiles x (8 ds_read_b128 + 16 MFMA
// under setprio) + 3-op argmax. Addr = VGPR boffB[kc] + compile-time imm
// (BUF*16384 + tc*8192 folds into the ds_read offset field, max 57840).
template <int BUF>
__device__ __forceinline__ void process_chunk(
    const bf16x8 (&afrag)[2][8],
    const int (&boffB)[8],
    float (&best)[2][4], int (&bidx)[2][4],
    int l15, int ct)
{
    const float* nlds = (const float*)lds_raw;
#pragma unroll
    for (int tc = 0; tc < 2; ++tc) {
        const int col = ct * CHUNK + tc * 16 + l15;
        const float nh = nlds[ct * CHUNK + tc * 16 + l15];
        f32x4 acc0 = {nh, nh, nh, nh};
        f32x4 acc1 = {nh, nh, nh, nh};
        bf16x8 bfr[8];
#pragma unroll
        for (int kc = 0; kc < 8; ++kc)
            bfr[kc] = *(const bf16x8*)(lds_raw + boffB[kc]
                                       + BUF * BUFB + tc * 8192);
        __builtin_amdgcn_s_setprio(1);
#pragma unroll
        for (int kc = 0; kc < 8; ++kc) {
            acc0 = __builtin_amdgcn_mfma_f32_16x16x32_bf16(
                afrag[0][kc], bfr[kc], acc0, 0, 0, 0);
            acc1 = __builtin_amdgcn_mfma_f32_16x16x32_bf16(
                afrag[1][kc], bfr[kc], acc1, 0, 0, 0);
        }
        __builtin_amdgcn_s_setprio(0);
        // C/D: col = lane&15, row = (lane>>4)*4 + r  [HW-verified]
#pragma unroll
        for (int r = 0; r < 4; ++r) {
            float s0 = acc0[r];
            bool g0 = s0 > best[0][r];
            bidx[0][r] = g0 ? col : bidx[0][r];
            best[0][r] = fmaxf(best[0][r], s0);
            float s1 = acc1[r];
            bool g1 = s1 > best[1][r];
            bidx[1][r] = g1 ? col : bidx[1][r];
            best[1][r] = fmaxf(best[1][r], s1);
        }
    }
}

__global__ __launch_bounds__(256, 2)
void vq_argmin(const float* __restrict__ X,       // [65536][256] f32
               const ushort* __restrict__ ETbf,   // [4096][256] bf16
               const float* __restrict__ nenh,    // [4096] = -0.5*||e||^2
               int* __restrict__ idxout)          // [65536]
{
    const int tid  = threadIdx.x;
    const int lane = tid & 63;
    const int wave = tid >> 6;          // 0..3
    const int l15  = lane & 15;
    const int g    = lane >> 4;         // 0..3
    const int m    = l15 & 7;           // read-side swizzle key
    const long rowbase = (long)blockIdx.x * 128 + wave * 32;

    // Per-lane global source offsets for staging (XOR-swizzled, as R4/R5).
    int soff[4];
#pragma unroll
    for (int j = 0; j < 4; ++j) {
        const int o    = wave * 4096 + j * 1024 + lane * 16;
        const int col0 = o >> 9;           // 0..31 within chunk
        const int cph  = (o >> 4) & 31;    // physical 16B slot in row
        soff[j] = (col0 << 9) + ((cph ^ (col0 & 7)) << 4);
    }

    // Prologue staging: nenh (16KB) + chunks 0,1,2. 16 issues/wave total.
#pragma unroll
    for (int j = 0; j < 4; ++j) {
        int o = wave * 4096 + j * 1024 + lane * 16;
        __builtin_amdgcn_global_load_lds(
            (const __attribute__((address_space(1))) unsigned*)((const char*)nenh + o),
            (__attribute__((address_space(3))) unsigned*)
                (lds_raw + wave * 4096 + j * 1024),
            16, 0, 0);
    }
    stage_chunk<0>((const char*)ETbf, soff, wave, 0);
    stage_chunk<1>((const char*)ETbf, soff, wave, 1);
    stage_chunk<2>((const char*)ETbf, soff, wave, 2);

    // A fragments resident in VGPRs: lane holds A[row=l15][k=g*64+kc*8+j].
    bf16x8 afrag[2][8];
#pragma unroll
    for (int rt = 0; rt < 2; ++rt) {
        const float* xr = X + (rowbase + rt * 16 + l15) * DIM;
#pragma unroll
        for (int kc = 0; kc < 8; ++kc) {
            int k0 = g * 64 + kc * 8;
            float4 v0 = *(const float4*)(xr + k0);
            float4 v1 = *(const float4*)(xr + k0 + 4);
            bf16x8 f;
            f[0] = f2bf(v0.x); f[1] = f2bf(v0.y);
            f[2] = f2bf(v0.z); f[3] = f2bf(v0.w);
            f[4] = f2bf(v1.x); f[5] = f2bf(v1.y);
            f[6] = f2bf(v1.z); f[7] = f2bf(v1.w);
            afrag[rt][kc] = f;
        }
    }

    // LDS read base offsets (include bufs base NENHB): row l15 of the
    // 16-col tile, slot (g*8+kc) swizzled by m.
    int boffB[8];
#pragma unroll
    for (int kc = 0; kc < 8; ++kc)
        boffB[kc] = NENHB + l15 * 512 + ((((g << 3) + kc) ^ m) << 4);

    float best[2][4];
    int   bidx[2][4];
#pragma unroll
    for (int rt = 0; rt < 2; ++rt)
#pragma unroll
        for (int r = 0; r < 4; ++r) { best[rt][r] = -3.4e38f; bidx[rt][r] = 0x7fffffff; }

    const char* etb = (const char*)ETbf;

    // Main loop: chunks 0..123 in groups of 4 (buf = ct%4). During chunk ct,
    // stage ct+3 (max target 126). Wait vmcnt(8): outstanding = stages for
    // ct+1, ct+2 (4 each); ct's stages (8 issues older) forced retired.
    for (int gq = 0; gq < 31; ++gq) {
        const int ct = gq * 4;
        WAITV(8); __builtin_amdgcn_s_barrier();
        stage_chunk<3>(etb, soff, wave, ct + 3);
        process_chunk<0>(afrag, boffB, best, bidx, l15, ct);
        WAITV(8); __builtin_amdgcn_s_barrier();
        stage_chunk<0>(etb, soff, wave, ct + 4);
        process_chunk<1>(afrag, boffB, best, bidx, l15, ct + 1);
        WAITV(8); __builtin_amdgcn_s_barrier();
        stage_chunk<1>(etb, soff, wave, ct + 5);
        process_chunk<2>(afrag, boffB, best, bidx, l15, ct + 2);
        WAITV(8); __builtin_amdgcn_s_barrier();
        stage_chunk<2>(etb, soff, wave, ct + 6);
        process_chunk<3>(afrag, boffB, best, bidx, l15, ct + 3);
    }
    // Tail: chunks 124..127. 124 stages 127; then drain progressively.
    WAITV(8); __builtin_amdgcn_s_barrier();
    stage_chunk<3>(etb, soff, wave, 127);
    process_chunk<0>(afrag, boffB, best, bidx, l15, 124);
    WAITV(8); __builtin_amdgcn_s_barrier();
    process_chunk<1>(afrag, boffB, best, bidx, l15, 125);
    WAITV(4); __builtin_amdgcn_s_barrier();
    process_chunk<2>(afrag, boffB, best, bidx, l15, 126);
    WAITV(0); __builtin_amdgcn_s_barrier();
    process_chunk<3>(afrag, boffB, best, bidx, l15, 127);

    // Reduce across the 16 lanes holding the same row (xor in low 4 bits).
#pragma unroll
    for (int rt = 0; rt < 2; ++rt) {
#pragma unroll
        for (int r = 0; r < 4; ++r) {
            float v = best[rt][r];
            int   ix = bidx[rt][r];
#pragma unroll
            for (int off = 1; off < 16; off <<= 1) {
                float ov = __shfl_xor(v, off, 64);
                int   oi = __shfl_xor(ix, off, 64);
                if (ov > v || (ov == v && oi < ix)) { v = ov; ix = oi; }
            }
            if (l15 == 0) {
                long row = rowbase + rt * 16 + g * 4 + r;
                idxout[row] = ix;
            }
        }
    }
}

// ---------------------------------------------------------------------------
// Gather nearest codebook rows (coalesced from ET32) + histogram
// ---------------------------------------------------------------------------
__global__ void vq_gather(const int* __restrict__ idxin,
                          const float* __restrict__ ET32,
                          float* __restrict__ out,
                          unsigned* __restrict__ counts)
{
    const int tid = threadIdx.x;
    const long n  = (long)blockIdx.x * 4 + (tid >> 6);
    const int d4  = tid & 63;
    const int idx = idxin[n];
    float4 v = *(const float4*)(ET32 + (size_t)idx * DIM + d4 * 4);
    *(float4*)(out + n * DIM + d4 * 4) = v;
    if (d4 == 0) atomicAdd(&counts[idx], 1u);
}

// ---------------------------------------------------------------------------
// Perplexity = exp(-sum p*log(p+1e-10)), p = counts/N
// ---------------------------------------------------------------------------
__global__ void vq_perplexity(const unsigned* __restrict__ counts, float* __restrict__ outp)
{
    __shared__ float wsum[4];
    const int tid = threadIdx.x;
    float s = 0.0f;
    for (int k = tid; k < KCB; k += 256) {
        float p = (float)counts[k] * (1.0f / (float)NROWS);
        s += p * logf(p + 1e-10f);
    }
#pragma unroll
    for (int off = 32; off >= 1; off >>= 1) s += __shfl_down(s, off, 64);
    if ((tid & 63) == 0) wsum[tid >> 6] = s;
    __syncthreads();
    if (tid == 0) outp[0] = expf(-(wsum[0] + wsum[1] + wsum[2] + wsum[3]));
}

// ---------------------------------------------------------------------------
extern "C" void kernel_launch(void* const* d_in, const int* in_sizes, int n_in,
                              void* d_out, int out_size, void* d_ws, size_t ws_size,
                              hipStream_t stream)
{
    const float* X = (const float*)d_in[0];
    const float* E = (const float*)d_in[1];
    float* out = (float*)d_out;

    char* ws = (char*)d_ws;
    float*    ET32   = (float*)ws;                                   // 4 MB
    ushort*   ETbf   = (ushort*)(ws + (size_t)KCB * DIM * 4);        // 2 MB
    float*    nenh   = (float*)(ws + (size_t)KCB * DIM * 6);         // 16 KB
    int*      idxbuf = (int*)(ws + (size_t)KCB * DIM * 6 + KCB * 4); // 256 KB
    unsigned* counts = (unsigned*)(ws + (size_t)KCB * DIM * 6 + KCB * 4 + NROWS * 4); // 16 KB

    hipMemsetAsync(counts, 0, KCB * sizeof(unsigned), stream);

    prep_transpose<<<dim3(KCB / 64, DIM / 64), dim3(256), 0, stream>>>(E, ET32, ETbf);
    prep_enorm<<<KCB / 256, dim3(256), 0, stream>>>(E, nenh);
    vq_argmin<<<NROWS / 128, dim3(256), 0, stream>>>(X, ETbf, nenh, idxbuf);
    vq_gather<<<NROWS / 4, dim3(256), 0, stream>>>(idxbuf, ET32, out, counts);
    vq_perplexity<<<1, dim3(256), 0, stream>>>(counts, out + (size_t)NROWS * DIM);
}

// Round 7
// 182.178 us; speedup vs baseline: 1.3856x; 1.0535x over previous
//
#include <hip/hip_runtime.h>
#include <hip/hip_bf16.h>

// Problem constants: x [4,32,32,16,256] -> N=65536 rows, D=256
// embeddings [256, 4096] -> D=256, K=4096
#define NROWS 65536
#define DIM   256
#define KCB   4096
#define CHUNK 32                 // codebook cols per chunk (16KB)
#define NCH   (KCB / CHUNK)      // 128 chunks
#define NBUF  4                  // buffer ring depth
#define BUFB  16384              // bytes per buffer
#define NENH_BASE (NBUF * BUFB)  // nenh f32[4096] at end of LDS (16KB)

typedef __attribute__((ext_vector_type(8))) short bf16x8;  // 8 bf16, 4 VGPRs
typedef __attribute__((ext_vector_type(4))) float f32x4;

#define WAITV0 asm volatile("s_waitcnt vmcnt(0)" ::: "memory")
#define WAITV4 asm volatile("s_waitcnt vmcnt(4)" ::: "memory")
#define WAITV8 asm volatile("s_waitcnt vmcnt(8)" ::: "memory")

__device__ inline short f2bf(float f) {
    __hip_bfloat16 h = __float2bfloat16(f);
    return *reinterpret_cast<short*>(&h);
}

// ---------------------------------------------------------------------------
// Prep 1: tiled transpose E[256][4096] -> ET32[4096][256] (f32) + ETbf (bf16)
// ---------------------------------------------------------------------------
__global__ void prep_transpose(const float* __restrict__ E,
                               float* __restrict__ ET32,
                               ushort* __restrict__ ETbf)
{
    __shared__ float tile[64][65];
    const int kb = blockIdx.x * 64;
    const int db = blockIdx.y * 64;
    const int lo = threadIdx.x & 63;
    const int hi = threadIdx.x >> 6;

#pragma unroll
    for (int i = 0; i < 16; ++i) {
        int d = i * 4 + hi;
        tile[lo][d] = E[(size_t)(db + d) * KCB + kb + lo];
    }
    __syncthreads();
#pragma unroll
    for (int i = 0; i < 16; ++i) {
        int k = i * 4 + hi;
        float v = tile[k][lo];
        size_t off = (size_t)(kb + k) * DIM + db + lo;
        ET32[off] = v;
        ETbf[off] = (ushort)f2bf(v);
    }
}

// ---------------------------------------------------------------------------
// Prep 2: nenh[k] = -0.5*||e_k||^2 (fp32-exact); score = sim + nenh.
// ---------------------------------------------------------------------------
__global__ void prep_enorm(const float* __restrict__ E, float* __restrict__ nenh)
{
    int k = blockIdx.x * 256 + threadIdx.x;
    float s = 0.0f;
#pragma unroll 8
    for (int d = 0; d < DIM; ++d) {
        float v = E[(size_t)d * KCB + k];
        s = fmaf(v, v, s);
    }
    nenh[k] = -0.5f * s;
}

// ---------------------------------------------------------------------------
// vq_argmin: 4 waves x 32 rows; 128 chunks of 32 cols; ring-4 LDS + counted
// vmcnt(4) (current AND next chunk staged at loop top). Register-set double
// buffer (bA/bB) keeps ds_reads one MFMA-cluster AHEAD so the LDS pipe runs
// in the shadow of in-flight MFMAs (m201-style interleave).
// LDS map: [0, 64K) ring buffers; [64K, 80K) nenh. 80KB -> 2 blocks/CU.
// ---------------------------------------------------------------------------
__shared__ char lds_raw[NBUF * BUFB + 16384];

// Stage chunk ct (32 cols x 512B = 16KB) into buffer BUF. 4 waves x 4 issues
// x 1KB. LDS dest linear; XOR swizzle (slot ^= col&7) pre-applied to the
// per-lane GLOBAL source offset (both-sides rule, verified R4-R6).
template <int BUF>
__device__ __forceinline__ void stage_chunk(
    const char* __restrict__ etb, const int (&soff)[4], int wave, int ct)
{
    const char* base = etb + (size_t)ct * (CHUNK * 512);
#pragma unroll
    for (int j = 0; j < 4; ++j) {
        __builtin_amdgcn_global_load_lds(
            (const __attribute__((address_space(1))) unsigned*)(base + soff[j]),
            (__attribute__((address_space(3))) unsigned*)
                (lds_raw + BUF * BUFB + wave * 4096 + j * 1024),
            16, 0, 0);
    }
}

// Read one fragment batch: 8x ds_read_b128 (B fragments for a 16-col tile)
// + 1x ds_read_b32 (nh). Addr = VGPR boffB[kc] + compile-time imm (<=57K).
template <int BUF, int TC>
__device__ __forceinline__ void read_batch(
    const int (&boffB)[8], int nhbyte, bf16x8 (&bfr)[8], float& nh)
{
#pragma unroll
    for (int kc = 0; kc < 8; ++kc)
        bfr[kc] = *(const bf16x8*)(lds_raw + BUF * BUFB + TC * 8192 + boffB[kc]);
    nh = *(const float*)(lds_raw + NENH_BASE + nhbyte);
}

// 16 MFMA under setprio + 3-op argmax. col for C/D: lane&15 (HW-verified).
__device__ __forceinline__ void mfma_cluster(
    const bf16x8 (&afrag)[2][8], const bf16x8 (&bfr)[8], float nh,
    float (&best)[2][4], int (&bidx)[2][4], int col)
{
    f32x4 acc0 = {nh, nh, nh, nh};
    f32x4 acc1 = {nh, nh, nh, nh};
    __builtin_amdgcn_s_setprio(1);
#pragma unroll
    for (int kc = 0; kc < 8; ++kc) {
        acc0 = __builtin_amdgcn_mfma_f32_16x16x32_bf16(afrag[0][kc], bfr[kc], acc0, 0, 0, 0);
        acc1 = __builtin_amdgcn_mfma_f32_16x16x32_bf16(afrag[1][kc], bfr[kc], acc1, 0, 0, 0);
    }
    __builtin_amdgcn_s_setprio(0);
#pragma unroll
    for (int r = 0; r < 4; ++r) {
        float s0 = acc0[r];
        bool g0 = s0 > best[0][r];
        bidx[0][r] = g0 ? col : bidx[0][r];
        best[0][r] = fmaxf(best[0][r], s0);
        float s1 = acc1[r];
        bool g1 = s1 > best[1][r];
        bidx[1][r] = g1 ? col : bidx[1][r];
        best[1][r] = fmaxf(best[1][r], s1);
    }
}

// One chunk: WAITV -> barrier -> stage(ct+3) -> R(ct,1)->bB -> MFMA(bA)
// -> R(ct+1,0)->bA -> MFMA(bB). Reads stay one cluster ahead of their use.
// Buffer-write-conflict check: during ct, reads touch BUF and (BUF+1)&3;
// stage targets (BUF+3)&3 — disjoint. WAITV(4) retires ct+1's stages (and
// every wave does so before the barrier => cross-wave visibility).
template <int BUF, int WN, bool STG, bool RA>
__device__ __forceinline__ void chunk_step(
    const char* __restrict__ etb, const int (&soff)[4], int wave, int ct,
    const int (&boffB)[8], int l15,
    const bf16x8 (&afrag)[2][8],
    bf16x8 (&bA)[8], bf16x8 (&bB)[8], float& nhA, float& nhB,
    float (&best)[2][4], int (&bidx)[2][4])
{
    if constexpr (WN == 4) { WAITV4; } else { WAITV0; }
    __builtin_amdgcn_s_barrier();
    __builtin_amdgcn_sched_barrier(0);
    if constexpr (STG) stage_chunk<(BUF + 3) & 3>(etb, soff, wave, ct + 3);
    read_batch<BUF, 1>(boffB, ct * 128 + 64 + l15 * 4, bB, nhB);
    mfma_cluster(afrag, bA, nhA, best, bidx, ct * CHUNK + l15);
    if constexpr (RA)
        read_batch<(BUF + 1) & 3, 0>(boffB, (ct + 1) * 128 + l15 * 4, bA, nhA);
    mfma_cluster(afrag, bB, nhB, best, bidx, ct * CHUNK + 16 + l15);
}

__global__ __launch_bounds__(256, 2)
void vq_argmin(const float* __restrict__ X,       // [65536][256] f32
               const ushort* __restrict__ ETbf,   // [4096][256] bf16
               const float* __restrict__ nenh,    // [4096] = -0.5*||e||^2
               int* __restrict__ idxout)          // [65536]
{
    const int tid  = threadIdx.x;
    const int lane = tid & 63;
    const int wave = tid >> 6;          // 0..3
    const int l15  = lane & 15;
    const int g    = lane >> 4;         // 0..3
    const int m    = l15 & 7;           // read-side swizzle key
    const long rowbase = (long)blockIdx.x * 128 + wave * 32;
    const char* etb = (const char*)ETbf;

    // A fragments resident in VGPRs: lane holds A[row=l15][k=g*64+kc*8+j].
    bf16x8 afrag[2][8];
#pragma unroll
    for (int rt = 0; rt < 2; ++rt) {
        const float* xr = X + (rowbase + rt * 16 + l15) * DIM;
#pragma unroll
        for (int kc = 0; kc < 8; ++kc) {
            int k0 = g * 64 + kc * 8;
            float4 v0 = *(const float4*)(xr + k0);
            float4 v1 = *(const float4*)(xr + k0 + 4);
            bf16x8 f;
            f[0] = f2bf(v0.x); f[1] = f2bf(v0.y);
            f[2] = f2bf(v0.z); f[3] = f2bf(v0.w);
            f[4] = f2bf(v1.x); f[5] = f2bf(v1.y);
            f[6] = f2bf(v1.z); f[7] = f2bf(v1.w);
            afrag[rt][kc] = f;
        }
    }

    // Per-lane global source offsets for staging (XOR-swizzled, as R4-R6).
    int soff[4];
#pragma unroll
    for (int j = 0; j < 4; ++j) {
        const int o    = wave * 4096 + j * 1024 + lane * 16;
        const int col0 = o >> 9;           // 0..31 within chunk
        const int cph  = (o >> 4) & 31;    // physical 16B slot in row
        soff[j] = (col0 << 9) + ((cph ^ (col0 & 7)) << 4);
    }

    // LDS read offsets: row l15 of the 16-col tile, slot (g*8+kc) ^ m.
    int boffB[8];
#pragma unroll
    for (int kc = 0; kc < 8; ++kc)
        boffB[kc] = l15 * 512 + ((((g << 3) + kc) ^ m) << 4);

    // Prologue staging: nenh (16KB, at NENH_BASE) + chunks 0,1,2.
#pragma unroll
    for (int j = 0; j < 4; ++j) {
        int o = wave * 4096 + j * 1024 + lane * 16;
        __builtin_amdgcn_global_load_lds(
            (const __attribute__((address_space(1))) unsigned*)((const char*)nenh + o),
            (__attribute__((address_space(3))) unsigned*)
                (lds_raw + NENH_BASE + wave * 4096 + j * 1024),
            16, 0, 0);
    }
    stage_chunk<0>(etb, soff, wave, 0);
    stage_chunk<1>(etb, soff, wave, 1);
    stage_chunk<2>(etb, soff, wave, 2);

    float best[2][4];
    int   bidx[2][4];
#pragma unroll
    for (int rt = 0; rt < 2; ++rt)
#pragma unroll
        for (int r = 0; r < 4; ++r) { best[rt][r] = -3.4e38f; bidx[rt][r] = 0x7fffffff; }

    bf16x8 bA[8], bB[8];
    float nhA, nhB;

    // Prologue wait: retire nenh + chunk0 (leaves chunks 1,2 in flight).
    WAITV8;
    __builtin_amdgcn_s_barrier();
    __builtin_amdgcn_sched_barrier(0);
    read_batch<0, 0>(boffB, 0 + l15 * 4, bA, nhA);

    for (int gq = 0; gq < 31; ++gq) {
        const int ct = gq * 4;
        chunk_step<0, 4, true, true>(etb, soff, wave, ct + 0, boffB, l15,
                                     afrag, bA, bB, nhA, nhB, best, bidx);
        chunk_step<1, 4, true, true>(etb, soff, wave, ct + 1, boffB, l15,
                                     afrag, bA, bB, nhA, nhB, best, bidx);
        chunk_step<2, 4, true, true>(etb, soff, wave, ct + 2, boffB, l15,
                                     afrag, bA, bB, nhA, nhB, best, bidx);
        chunk_step<3, 4, true, true>(etb, soff, wave, ct + 3, boffB, l15,
                                     afrag, bA, bB, nhA, nhB, best, bidx);
    }
    // Tail: 124 (stages 127), 125, 126 (drain for 127 read-ahead), 127.
    chunk_step<0, 4, true,  true >(etb, soff, wave, 124, boffB, l15,
                                   afrag, bA, bB, nhA, nhB, best, bidx);
    chunk_step<1, 4, false, true >(etb, soff, wave, 125, boffB, l15,
                                   afrag, bA, bB, nhA, nhB, best, bidx);
    chunk_step<2, 0, false, true >(etb, soff, wave, 126, boffB, l15,
                                   afrag, bA, bB, nhA, nhB, best, bidx);
    chunk_step<3, 0, false, false>(etb, soff, wave, 127, boffB, l15,
                                   afrag, bA, bB, nhA, nhB, best, bidx);

    // Reduce across the 16 lanes holding the same row (xor in low 4 bits).
#pragma unroll
    for (int rt = 0; rt < 2; ++rt) {
#pragma unroll
        for (int r = 0; r < 4; ++r) {
            float v = best[rt][r];
            int   ix = bidx[rt][r];
#pragma unroll
            for (int off = 1; off < 16; off <<= 1) {
                float ov = __shfl_xor(v, off, 64);
                int   oi = __shfl_xor(ix, off, 64);
                if (ov > v || (ov == v && oi < ix)) { v = ov; ix = oi; }
            }
            if (l15 == 0) {
                long row = rowbase + rt * 16 + g * 4 + r;
                idxout[row] = ix;
            }
        }
    }
}

// ---------------------------------------------------------------------------
// Gather nearest codebook rows (coalesced from ET32) + histogram
// ---------------------------------------------------------------------------
__global__ void vq_gather(const int* __restrict__ idxin,
                          const float* __restrict__ ET32,
                          float* __restrict__ out,
                          unsigned* __restrict__ counts)
{
    const int tid = threadIdx.x;
    const long n  = (long)blockIdx.x * 4 + (tid >> 6);
    const int d4  = tid & 63;
    const int idx = idxin[n];
    float4 v = *(const float4*)(ET32 + (size_t)idx * DIM + d4 * 4);
    *(float4*)(out + n * DIM + d4 * 4) = v;
    if (d4 == 0) atomicAdd(&counts[idx], 1u);
}

// ---------------------------------------------------------------------------
// Perplexity = exp(-sum p*log(p+1e-10)), p = counts/N
// ---------------------------------------------------------------------------
__global__ void vq_perplexity(const unsigned* __restrict__ counts, float* __restrict__ outp)
{
    __shared__ float wsum[4];
    const int tid = threadIdx.x;
    float s = 0.0f;
    for (int k = tid; k < KCB; k += 256) {
        float p = (float)counts[k] * (1.0f / (float)NROWS);
        s += p * logf(p + 1e-10f);
    }
#pragma unroll
    for (int off = 32; off >= 1; off >>= 1) s += __shfl_down(s, off, 64);
    if ((tid & 63) == 0) wsum[tid >> 6] = s;
    __syncthreads();
    if (tid == 0) outp[0] = expf(-(wsum[0] + wsum[1] + wsum[2] + wsum[3]));
}

// ---------------------------------------------------------------------------
extern "C" void kernel_launch(void* const* d_in, const int* in_sizes, int n_in,
                              void* d_out, int out_size, void* d_ws, size_t ws_size,
                              hipStream_t stream)
{
    const float* X = (const float*)d_in[0];
    const float* E = (const float*)d_in[1];
    float* out = (float*)d_out;

    char* ws = (char*)d_ws;
    float*    ET32   = (float*)ws;                                   // 4 MB
    ushort*   ETbf   = (ushort*)(ws + (size_t)KCB * DIM * 4);        // 2 MB
    float*    nenh   = (float*)(ws + (size_t)KCB * DIM * 6);         // 16 KB
    int*      idxbuf = (int*)(ws + (size_t)KCB * DIM * 6 + KCB * 4); // 256 KB
    unsigned* counts = (unsigned*)(ws + (size_t)KCB * DIM * 6 + KCB * 4 + NROWS * 4); // 16 KB

    hipMemsetAsync(counts, 0, KCB * sizeof(unsigned), stream);

    prep_transpose<<<dim3(KCB / 64, DIM / 64), dim3(256), 0, stream>>>(E, ET32, ETbf);
    prep_enorm<<<KCB / 256, dim3(256), 0, stream>>>(E, nenh);
    vq_argmin<<<NROWS / 128, dim3(256), 0, stream>>>(X, ETbf, nenh, idxbuf);
    vq_gather<<<NROWS / 4, dim3(256), 0, stream>>>(idxbuf, ET32, out, counts);
    vq_perplexity<<<1, dim3(256), 0, stream>>>(counts, out + (size_t)NROWS * DIM);
}